// Round 5
// baseline (2965.348 us; speedup 1.0000x reference)
//
#include <hip/hip_runtime.h>
#include <cstdint>
#include <cstddef>

// Problem constants (match reference)
#define NB 8          // B clouds
#define NP 4096       // N points per cloud
#define NC 64         // C feature channels
#define NM 2048       // M sampled centroids
#define NK 64         // K max neighbors
#define H1 64
#define H2 64
#define NOUT 128
#define CAND_CAP 1024
#define MSG_LD 68     // padded LDS leading dim

static __device__ __forceinline__ float sq3(float x, float y, float z) {
    // ((x*x + y*y) + z*z) with no FMA contraction, matching numpy order
    return __fadd_rn(__fadd_rn(__fmul_rn(x, x), __fmul_rn(y, y)), __fmul_rn(z, z));
}

// f32 max with DPP-shifted partner; old = own value so invalid lanes are identity
#define DPP_MAX(x, ctrl)                                                       \
    do {                                                                       \
        int _yi = __builtin_amdgcn_update_dpp(__float_as_int(x),               \
                                              __float_as_int(x), (ctrl),       \
                                              0xf, 0xf, false);                \
        (x) = fmaxf((x), __int_as_float(_yi));                                 \
    } while (0)

// ---------------------------------------------------------------------------
// Kernel 1: exact FPS per cloud (8 blocks x 512 threads).
// Points in registers (8/thread). Wave reduce = DPP v_max_f32 chain (VALU)
// + ballot; winner lane writes (u64 key, coords) to LDS. Cross-wave tree
// carries coords, so no dependent pts[last] read on the critical path.
// ---------------------------------------------------------------------------
__global__ __launch_bounds__(512, 1)
void fps_kernel(const float* __restrict__ pos,
                float4* __restrict__ p4,
                float* __restrict__ pos_s,
                float* __restrict__ batch_s)
{
    __shared__ float4 pts[NP];                  // 64 KB
    __shared__ int s_idx[NM];                   // 8 KB
    __shared__ unsigned long long redk[2][8];
    __shared__ float4 redc[2][8];

    const int b = blockIdx.x;
    const int t = threadIdx.x;
    const float* p = pos + (size_t)b * NP * 3;

    for (int j = t; j < NP; j += 512) {
        float x = p[j * 3 + 0], y = p[j * 3 + 1], z = p[j * 3 + 2];
        float4 q = make_float4(x, y, z, sq3(x, y, z));
        pts[j] = q;
        p4[b * NP + j] = q;
    }
    if (t == 0) s_idx[0] = 0;
    __syncthreads();

    // thread t owns points j = t + i*512, i in 0..7 (ascending i == ascending j)
    float rx[8], ry[8], rz[8], md[8];
#pragma unroll
    for (int i = 0; i < 8; ++i) {
        float4 q = pts[t + (i << 9)];
        rx[i] = q.x; ry[i] = q.y; rz[i] = q.z;
        md[i] = __builtin_inff();
    }

    float4 L0 = pts[0];
    float Lx = L0.x, Ly = L0.y, Lz = L0.z;
    const int w = t >> 6;

    for (int m = 1; m < NM; ++m) {
        float vv[8];
#pragma unroll
        for (int i = 0; i < 8; ++i) {
            float dx = __fsub_rn(rx[i], Lx);
            float dy = __fsub_rn(ry[i], Ly);
            float dz = __fsub_rn(rz[i], Lz);
            float d = sq3(dx, dy, dz);
            float v = fminf(md[i], d);
            md[i] = v;
            vv[i] = v;
        }
        // depth-3 pairwise tree; strict '>' keeps the smaller index on ties
        float nv[4]; int ni[4];
#pragma unroll
        for (int i = 0; i < 4; ++i) {
            bool c = vv[2 * i + 1] > vv[2 * i];
            nv[i] = c ? vv[2 * i + 1] : vv[2 * i];
            ni[i] = 2 * i + (c ? 1 : 0);
        }
        float mv[2]; int mi[2];
#pragma unroll
        for (int i = 0; i < 2; ++i) {
            bool c = nv[2 * i + 1] > nv[2 * i];
            mv[i] = c ? nv[2 * i + 1] : nv[2 * i];
            mi[i] = c ? ni[2 * i + 1] : ni[2 * i];
        }
        bool cf = mv[1] > mv[0];
        float bv = cf ? mv[1] : mv[0];
        int bi = cf ? mi[1] : mi[0];

        // DPP wave-max of bv (lane 63 holds full max), broadcast via readlane
        float wxv = bv;
        DPP_MAX(wxv, 0x111);   // row_shr:1
        DPP_MAX(wxv, 0x112);   // row_shr:2
        DPP_MAX(wxv, 0x114);   // row_shr:4
        DPP_MAX(wxv, 0x118);   // row_shr:8
        DPP_MAX(wxv, 0x142);   // row_bcast:15
        DPP_MAX(wxv, 0x143);   // row_bcast:31
        float wmax = __int_as_float(
            __builtin_amdgcn_readlane(__float_as_int(wxv), 63));

        bool mine = (bv == wmax);
        unsigned long long tie = __ballot(mine);
        const int par = m & 1;

        if (__popcll(tie) == 1) {
            if (mine) {
                unsigned myj = (unsigned)t + ((unsigned)bi << 9);
                float a0 = (bi & 1) ? rx[1] : rx[0];
                float a1 = (bi & 1) ? rx[3] : rx[2];
                float a2 = (bi & 1) ? rx[5] : rx[4];
                float a3 = (bi & 1) ? rx[7] : rx[6];
                float b0 = (bi & 2) ? a1 : a0;
                float b1 = (bi & 2) ? a3 : a2;
                float cx = (bi & 4) ? b1 : b0;
                a0 = (bi & 1) ? ry[1] : ry[0];
                a1 = (bi & 1) ? ry[3] : ry[2];
                a2 = (bi & 1) ? ry[5] : ry[4];
                a3 = (bi & 1) ? ry[7] : ry[6];
                b0 = (bi & 2) ? a1 : a0;
                b1 = (bi & 2) ? a3 : a2;
                float cy = (bi & 4) ? b1 : b0;
                a0 = (bi & 1) ? rz[1] : rz[0];
                a1 = (bi & 1) ? rz[3] : rz[2];
                a2 = (bi & 1) ? rz[5] : rz[4];
                a3 = (bi & 1) ? rz[7] : rz[6];
                b0 = (bi & 2) ? a1 : a0;
                b1 = (bi & 2) ? a3 : a2;
                float cz = (bi & 4) ? b1 : b0;
                redk[par][w] =
                    ((unsigned long long)__float_as_uint(bv) << 32) |
                    (unsigned long long)(0xFFFFFFFFu - myj);
                redc[par][w] = make_float4(cx, cy, cz, 0.f);
            }
        } else {
            // rare exact-tie path: min j among tied lanes (exact argmax order)
            unsigned myj = (unsigned)t + ((unsigned)bi << 9);
            unsigned jj = mine ? myj : 0xFFFFFFFFu;
#pragma unroll
            for (int o = 32; o > 0; o >>= 1) {
                unsigned oj = __shfl_xor(jj, o, 64);
                jj = (oj < jj) ? oj : jj;
            }
            if (mine && myj == jj) {
                float a0 = (bi & 1) ? rx[1] : rx[0];
                float a1 = (bi & 1) ? rx[3] : rx[2];
                float a2 = (bi & 1) ? rx[5] : rx[4];
                float a3 = (bi & 1) ? rx[7] : rx[6];
                float b0 = (bi & 2) ? a1 : a0;
                float b1 = (bi & 2) ? a3 : a2;
                float cx = (bi & 4) ? b1 : b0;
                a0 = (bi & 1) ? ry[1] : ry[0];
                a1 = (bi & 1) ? ry[3] : ry[2];
                a2 = (bi & 1) ? ry[5] : ry[4];
                a3 = (bi & 1) ? ry[7] : ry[6];
                b0 = (bi & 2) ? a1 : a0;
                b1 = (bi & 2) ? a3 : a2;
                float cy = (bi & 4) ? b1 : b0;
                a0 = (bi & 1) ? rz[1] : rz[0];
                a1 = (bi & 1) ? rz[3] : rz[2];
                a2 = (bi & 1) ? rz[5] : rz[4];
                a3 = (bi & 1) ? rz[7] : rz[6];
                b0 = (bi & 2) ? a1 : a0;
                b1 = (bi & 2) ? a3 : a2;
                float cz = (bi & 4) ? b1 : b0;
                redk[par][w] =
                    ((unsigned long long)__float_as_uint(bv) << 32) |
                    (unsigned long long)(0xFFFFFFFFu - jj);
                redc[par][w] = make_float4(cx, cy, cz, 0.f);
            }
        }
        __syncthreads();

        unsigned long long gk = redk[par][0];
        float4 gc = redc[par][0];
#pragma unroll
        for (int ww = 1; ww < 8; ++ww) {
            unsigned long long k2 = redk[par][ww];
            float4 c2 = redc[par][ww];
            if (k2 > gk) { gk = k2; gc = c2; }
        }
        Lx = gc.x; Ly = gc.y; Lz = gc.z;
        if (t == 0)
            s_idx[m] = (int)(0xFFFFFFFFu - (unsigned)(gk & 0xFFFFFFFFull));
        // redk/redc ping-pong on parity; one barrier per iteration is race-free
    }
    __syncthreads();

    for (int m = t; m < NM; m += 512) {
        int j = s_idx[m];
        size_t o = (size_t)(b * NM + m);
        float4 q = pts[j];
        pos_s[o * 3 + 0] = q.x;
        pos_s[o * 3 + 1] = q.y;
        pos_s[o * 3 + 2] = q.z;
        batch_s[o] = (float)b;
    }
}

// ---------------------------------------------------------------------------
// Kernel 2: radius ball query + exact K-nearest-within-R set per centroid.
// One wave per centroid; 4 waves per block. Selection = binary search on the
// distance-bit threshold (output order is irrelevant: result is max-pooled).
// ---------------------------------------------------------------------------
__global__ __launch_bounds__(256, 1)
void ball_kernel(const float4* __restrict__ p4,
                 const float* __restrict__ pos_s,
                 int* __restrict__ nbr,
                 int* __restrict__ cnt_out)
{
    __shared__ unsigned long long cand[4][CAND_CAP];
    const float R2 = 0.04f;  // f32(R*R)

    const int wv = threadIdx.x >> 6;
    const int lane = threadIdx.x & 63;
    const int c = blockIdx.x * 4 + wv;         // centroid id in [0, B*M)
    const int b = c >> 11;                     // / NM
    const float4* pc = p4 + b * NP;

    const float sx = pos_s[c * 3 + 0];
    const float sy = pos_s[c * 3 + 1];
    const float sz = pos_s[c * 3 + 2];
    const float ps2 = sq3(sx, sy, sz);

    int n = 0;
    for (int j0 = 0; j0 < NP; j0 += 64) {
        int j = j0 + lane;
        float4 q = pc[j];
        float dot = __fadd_rn(__fadd_rn(__fmul_rn(sx, q.x), __fmul_rn(sy, q.y)),
                              __fmul_rn(sz, q.z));
        float d2 = __fsub_rn(__fadd_rn(ps2, q.w), __fmul_rn(2.0f, dot));
        d2 = fmaxf(d2, 0.0f);
        bool in = (d2 <= R2);
        unsigned long long mask = __ballot(in);
        if (in) {
            int off = __popcll(mask & ((1ull << lane) - 1ull));
            int slot = n + off;
            if (slot < CAND_CAP)
                cand[wv][slot] =
                    ((unsigned long long)__float_as_uint(d2) << 32) |
                    (unsigned long long)(unsigned)j;
        }
        n += __popcll(mask);
    }
    if (n > CAND_CAP) n = CAND_CAP;

    int* nb = nbr + (size_t)c * NK;
    if (n <= NK) {
        for (int i = lane; i < n; i += 64)
            nb[i] = (int)(cand[wv][i] & 0xFFFFFFFFull);
        if (lane == 0) cnt_out[c] = n;
    } else if (n <= 256) {
        unsigned long long k0 = cand[wv][lane];
        unsigned long long k1 = (lane + 64  < n) ? cand[wv][lane + 64]  : ~0ull;
        unsigned long long k2 = (lane + 128 < n) ? cand[wv][lane + 128] : ~0ull;
        unsigned long long k3 = (lane + 192 < n) ? cand[wv][lane + 192] : ~0ull;
        unsigned d0 = (unsigned)(k0 >> 32), d1 = (unsigned)(k1 >> 32);
        unsigned d2b = (unsigned)(k2 >> 32), d3 = (unsigned)(k3 >> 32);

        unsigned lo = 0u, hi = __float_as_uint(R2) + 1u;
        while (hi - lo > 1u) {
            unsigned mid = (lo + hi) >> 1;
            int cc = (int)(d0 < mid) + (int)(d1 < mid) +
                     (int)(d2b < mid) + (int)(d3 < mid);
            int tot = __popcll(__ballot(cc > 0)) + __popcll(__ballot(cc > 1)) +
                      __popcll(__ballot(cc > 2)) + __popcll(__ballot(cc > 3));
            if (tot >= NK) hi = mid; else lo = mid;
        }
        const unsigned D = lo;
        bool l0 = d0 < D, l1 = d1 < D, l2 = d2b < D, l3 = d3 < D;
        bool e0 = d0 == D, e1 = d1 == D, e2 = d2b == D, e3 = d3 == D;
        int mcnt = __popcll(__ballot(l0)) + __popcll(__ballot(l1)) +
                   __popcll(__ballot(l2)) + __popcll(__ballot(l3));
        int t64 = NK - mcnt;
        unsigned long long E0 = __ballot(e0), E1 = __ballot(e1);
        unsigned long long E2 = __ballot(e2), E3 = __ballot(e3);
        unsigned long long lt = (1ull << lane) - 1ull;
        int p0 = __popcll(E0), p1 = __popcll(E1), p2 = __popcll(E2);
        bool t0 = e0 && (__popcll(E0 & lt) < t64);
        bool t1 = e1 && (p0 + __popcll(E1 & lt) < t64);
        bool t2 = e2 && (p0 + p1 + __popcll(E2 & lt) < t64);
        bool t3 = e3 && (p0 + p1 + p2 + __popcll(E3 & lt) < t64);
        bool i0 = l0 || t0, i1 = l1 || t1, i2 = l2 || t2, i3 = l3 || t3;
        unsigned long long M0 = __ballot(i0), M1 = __ballot(i1);
        unsigned long long M2 = __ballot(i2), M3 = __ballot(i3);
        int b1 = __popcll(M0), b2 = b1 + __popcll(M1), b3 = b2 + __popcll(M2);
        if (i0) nb[__popcll(M0 & lt)]      = (int)(k0 & 0xFFFFFFFFull);
        if (i1) nb[b1 + __popcll(M1 & lt)] = (int)(k1 & 0xFFFFFFFFull);
        if (i2) nb[b2 + __popcll(M2 & lt)] = (int)(k2 & 0xFFFFFFFFull);
        if (i3) nb[b3 + __popcll(M3 & lt)] = (int)(k3 & 0xFFFFFFFFull);
        if (lane == 0) cnt_out[c] = NK;
    } else {
        for (int r = 0; r < NK; ++r) {
            unsigned long long lmin = ~0ull;
            int lslot = -1;
            for (int i = lane; i < n; i += 64) {
                unsigned long long v = cand[wv][i];
                if (v < lmin) { lmin = v; lslot = i; }
            }
            unsigned long long gmin = lmin;
#pragma unroll
            for (int o = 32; o > 0; o >>= 1) {
                unsigned long long other = __shfl_xor(gmin, o, 64);
                gmin = (other < gmin) ? other : gmin;
            }
            if (lmin == gmin && lslot >= 0) {
                cand[wv][lslot] = ~0ull;
                nb[r] = (int)(gmin & 0xFFFFFFFFull);
            }
        }
        if (lane == 0) cnt_out[c] = NK;
    }
}

// ---------------------------------------------------------------------------
// Kernel 3: gather + 3-layer MLP (f32) + masked max-pool. One block per
// centroid, 2 blocks/CU. Hidden layers stored [f][n] with a row-dependent
// column-slot XOR swizzle; layer outputs written as float4 (bank-floor).
// swz: physical col = col ^ X(row), X = ((q&3)<<2) ^ ((q&1)<<4), q = row>>4.
// Bijective within each row (XOR touches col bits 2-4 only).
// ---------------------------------------------------------------------------
static __device__ __forceinline__ int swz(int row, int col) {
    int q = row >> 4;
    return row * MSG_LD + (col ^ ((q & 3) << 2) ^ ((q & 1) << 4));
}

__global__ __launch_bounds__(256, 2)
void mlp_kernel(const float* __restrict__ x,
                const float4* __restrict__ p4,
                const float* __restrict__ W1, const float* __restrict__ B1,
                const float* __restrict__ W2, const float* __restrict__ B2,
                const float* __restrict__ W3, const float* __restrict__ B3,
                const int* __restrict__ nbr, const int* __restrict__ cnt_arr,
                const float* __restrict__ pos_s,
                float* __restrict__ out)
{
    __shared__ __attribute__((aligned(16))) float sW1[67 * 64];
    __shared__ __attribute__((aligned(16))) float sW2[64 * 64];
    __shared__ float sB1[64], sB2[64], sB3[128];
    __shared__ __attribute__((aligned(16))) float msg[67 * MSG_LD]; // also hB
    __shared__ __attribute__((aligned(16))) float hA[64 * MSG_LD];
    __shared__ int obuf[128];
    __shared__ int s_nb[64];

    const int t = threadIdx.x;
    const int c = blockIdx.x;
    const int b = c >> 11;
    const int cnt = cnt_arr[c];
    float* hB = msg;   // msg is dead after layer 1; reuse for layer-2 output

    if (t < 128) obuf[t] = 0;
    if (t < 64) s_nb[t] = (t < cnt) ? nbr[(size_t)c * NK + t] : -1;
    {
        const float4* W1v = (const float4*)W1;
        const float4* W2v = (const float4*)W2;
        float4* s1 = (float4*)sW1;
        float4* s2 = (float4*)sW2;
        for (int i = t; i < 67 * 16; i += 256) s1[i] = W1v[i];
        for (int i = t; i < 64 * 16; i += 256) s2[i] = W2v[i];
    }
    if (t < 64) { sB1[t] = B1[t]; sB2[t] = B2[t]; }
    if (t < 128) sB3[t] = B3[t];
    const float sx = pos_s[c * 3 + 0];
    const float sy = pos_s[c * 3 + 1];
    const float sz = pos_s[c * 3 + 2];
    __syncthreads();

    // gather x_j -> msg rows 0..63 (swizzled cols), rel -> rows 64..66
    {
        int n = t >> 2, q = t & 3;
        int j = s_nb[n];
        const float4* row = (const float4*)(x + ((size_t)b * NP + (j < 0 ? 0 : j)) * NC);
#pragma unroll
        for (int s = 0; s < 4; ++s) {
            int k4 = q * 4 + s;
            float4 v = (j >= 0) ? row[k4] : make_float4(0.f, 0.f, 0.f, 0.f);
            msg[swz(k4 * 4 + 0, n)] = v.x;
            msg[swz(k4 * 4 + 1, n)] = v.y;
            msg[swz(k4 * 4 + 2, n)] = v.z;
            msg[swz(k4 * 4 + 3, n)] = v.w;
        }
        if (t < 64) {
            int jj = s_nb[t];
            float rx = 0.f, ry = 0.f, rz = 0.f;
            if (jj >= 0) {
                float4 pj = p4[b * NP + jj];
                rx = __fsub_rn(pj.x, sx);
                ry = __fsub_rn(pj.y, sy);
                rz = __fsub_rn(pj.z, sz);
            }
            msg[swz(64, t)] = rx;
            msg[swz(65, t)] = ry;
            msg[swz(66, t)] = rz;
        }
    }
    __syncthreads();

    const int tn = (t >> 4) << 2;   // n0: 4 neighbors
    const int tf = (t & 15) << 2;   // f0: 4 features

    // ---- layer 1: [64n x 67k] @ [67k x 64f] -> hA
    {
        float acc[4][4];
#pragma unroll
        for (int i = 0; i < 4; ++i)
#pragma unroll
            for (int j = 0; j < 4; ++j) acc[i][j] = 0.f;
        for (int k = 0; k < 67; ++k) {
            float4 a = *(const float4*)&msg[swz(k, tn)];
            float4 w = *(const float4*)&sW1[k * 64 + tf];
            float av[4] = {a.x, a.y, a.z, a.w};
            float wv[4] = {w.x, w.y, w.z, w.w};
#pragma unroll
            for (int i = 0; i < 4; ++i)
#pragma unroll
                for (int j = 0; j < 4; ++j)
                    acc[i][j] = fmaf(av[i], wv[j], acc[i][j]);
        }
#pragma unroll
        for (int j = 0; j < 4; ++j) {
            float bias = sB1[tf + j];
            float4 o4 = make_float4(fmaxf(acc[0][j] + bias, 0.f),
                                    fmaxf(acc[1][j] + bias, 0.f),
                                    fmaxf(acc[2][j] + bias, 0.f),
                                    fmaxf(acc[3][j] + bias, 0.f));
            *(float4*)&hA[swz(tf + j, tn)] = o4;
        }
    }
    __syncthreads();

    // ---- layer 2: [64n x 64k] @ [64k x 64f] -> hB (aliases msg)
    {
        float acc[4][4];
#pragma unroll
        for (int i = 0; i < 4; ++i)
#pragma unroll
            for (int j = 0; j < 4; ++j) acc[i][j] = 0.f;
        for (int k = 0; k < 64; ++k) {
            float4 a = *(const float4*)&hA[swz(k, tn)];
            float4 w = *(const float4*)&sW2[k * 64 + tf];
            float av[4] = {a.x, a.y, a.z, a.w};
            float wv[4] = {w.x, w.y, w.z, w.w};
#pragma unroll
            for (int i = 0; i < 4; ++i)
#pragma unroll
                for (int j = 0; j < 4; ++j)
                    acc[i][j] = fmaf(av[i], wv[j], acc[i][j]);
        }
#pragma unroll
        for (int j = 0; j < 4; ++j) {
            float bias = sB2[tf + j];
            float4 o4 = make_float4(fmaxf(acc[0][j] + bias, 0.f),
                                    fmaxf(acc[1][j] + bias, 0.f),
                                    fmaxf(acc[2][j] + bias, 0.f),
                                    fmaxf(acc[3][j] + bias, 0.f));
            *(float4*)&hB[swz(tf + j, tn)] = o4;
        }
    }
    __syncthreads();

    // ---- layer 3: [64n x 64k] @ [64k x 128f] + masked max-pool (W3 from L2)
    {
        const int tf3 = (t & 15) << 3;  // 8 features
        const float4* W3v = (const float4*)W3;
        const int wbase = (t & 15) << 1;
        float acc[4][8];
#pragma unroll
        for (int i = 0; i < 4; ++i)
#pragma unroll
            for (int j = 0; j < 8; ++j) acc[i][j] = 0.f;
#pragma unroll 4
        for (int k = 0; k < 64; ++k) {
            float4 a = *(const float4*)&hB[swz(k, tn)];
            float4 w0 = W3v[k * 32 + wbase];
            float4 w1 = W3v[k * 32 + wbase + 1];
            float av[4] = {a.x, a.y, a.z, a.w};
            float wv[8] = {w0.x, w0.y, w0.z, w0.w, w1.x, w1.y, w1.z, w1.w};
#pragma unroll
            for (int i = 0; i < 4; ++i)
#pragma unroll
                for (int j = 0; j < 8; ++j)
                    acc[i][j] = fmaf(av[i], wv[j], acc[i][j]);
        }
#pragma unroll
        for (int j = 0; j < 8; ++j) {
            float bias = sB3[tf3 + j];
            float mx = -1.f;
#pragma unroll
            for (int i = 0; i < 4; ++i) {
                if (tn + i < cnt) {
                    float v = fmaxf(acc[i][j] + bias, 0.f);
                    mx = fmaxf(mx, v);
                }
            }
            if (mx >= 0.f) atomicMax(&obuf[tf3 + j], __float_as_int(mx));
        }
    }
    __syncthreads();
    if (t < 128) out[(size_t)c * NOUT + t] = __int_as_float(obuf[t]);
}

// ---------------------------------------------------------------------------
extern "C" void kernel_launch(void* const* d_in, const int* in_sizes, int n_in,
                              void* d_out, int out_size, void* d_ws, size_t ws_size,
                              hipStream_t stream)
{
    (void)in_sizes; (void)n_in; (void)out_size; (void)ws_size;
    const float* x   = (const float*)d_in[0];
    const float* pos = (const float*)d_in[1];
    // d_in[2] = batch (unused: batch[b][n] == b)
    const float* W1 = (const float*)d_in[3];
    const float* B1 = (const float*)d_in[4];
    const float* W2 = (const float*)d_in[5];
    const float* B2 = (const float*)d_in[6];
    const float* W3 = (const float*)d_in[7];
    const float* B3 = (const float*)d_in[8];

    float* out     = (float*)d_out;                       // [B,M,128]
    float* pos_s   = out + (size_t)NB * NM * NOUT;        // [B,M,3]
    float* batch_s = pos_s + (size_t)NB * NM * 3;         // [B,M]

    // workspace: p4 table (512 KB) | nbr (4 MB) | cnt (64 KB)  ~= 4.6 MB
    float4* p4 = (float4*)d_ws;
    int* nbr = (int*)((char*)d_ws + (512 << 10));
    int* cnt = (int*)((char*)d_ws + (512 << 10) + (4 << 20));

    fps_kernel<<<NB, 512, 0, stream>>>(pos, p4, pos_s, batch_s);
    ball_kernel<<<(NB * NM) / 4, 256, 0, stream>>>(p4, pos_s, nbr, cnt);
    mlp_kernel<<<NB * NM, 256, 0, stream>>>(x, p4, W1, B1, W2, B2, W3, B3,
                                            nbr, cnt, pos_s, out);
}

// Round 6
// 2039.723 us; speedup vs baseline: 1.4538x; 1.4538x over previous
//
#include <hip/hip_runtime.h>
#include <cstdint>
#include <cstddef>

// Problem constants (match reference)
#define NB 8          // B clouds
#define NP 4096       // N points per cloud
#define NC 64         // C feature channels
#define NM 2048       // M sampled centroids
#define NK 64         // K max neighbors
#define H1 64
#define H2 64
#define NOUT 128
#define CAND_CAP 1024
#define MSG_LD 68     // padded LDS leading dim

static __device__ __forceinline__ float sq3(float x, float y, float z) {
    // ((x*x + y*y) + z*z) with no FMA contraction, matching numpy order
    return __fadd_rn(__fadd_rn(__fmul_rn(x, x), __fmul_rn(y, y)), __fmul_rn(z, z));
}

// f32 max with DPP-shifted partner; old = own value so invalid lanes are identity
#define DPP_MAX(x, ctrl)                                                       \
    do {                                                                       \
        int _yi = __builtin_amdgcn_update_dpp(__float_as_int(x),               \
                                              __float_as_int(x), (ctrl),       \
                                              0xf, 0xf, false);                \
        (x) = fmaxf((x), __int_as_float(_yi));                                 \
    } while (0)

// ---------------------------------------------------------------------------
// Kernel 1: exact FPS per cloud (8 blocks x 512 threads).
// CONTIGUOUS ownership: thread t owns points j = 8t..8t+7, so within a wave,
// lane order == point-index order. Wave argmax = DPP v_max chain (pure VALU)
// + ballot; winner lane = lowest set bit (exact smallest-j tie-break); its
// in-lane offset fetched with one readlane. Key built in SGPRs, one LDS write
// per wave, single barrier per iteration.
// ---------------------------------------------------------------------------
__global__ __launch_bounds__(512, 1)
void fps_kernel(const float* __restrict__ pos,
                float4* __restrict__ p4,
                float* __restrict__ pos_s,
                float* __restrict__ batch_s)
{
    __shared__ float4 pts[NP];                  // 64 KB
    __shared__ int s_idx[NM];                   // 8 KB
    __shared__ unsigned long long red[2][8];

    const int b = blockIdx.x;
    const int t = threadIdx.x;
    const float* p = pos + (size_t)b * NP * 3;

    for (int j = t; j < NP; j += 512) {
        float x = p[j * 3 + 0], y = p[j * 3 + 1], z = p[j * 3 + 2];
        float4 q = make_float4(x, y, z, sq3(x, y, z));
        pts[j] = q;
        p4[b * NP + j] = q;
    }
    if (t == 0) s_idx[0] = 0;
    __syncthreads();

    // thread t owns points j = 8t + i, i in 0..7 (ascending i == ascending j)
    float rx[8], ry[8], rz[8], md[8];
#pragma unroll
    for (int i = 0; i < 8; ++i) {
        float4 q = pts[(t << 3) + i];
        rx[i] = q.x; ry[i] = q.y; rz[i] = q.z;
        md[i] = __builtin_inff();
    }

    const int w = t >> 6;
    int last = 0;

    for (int m = 1; m < NM; ++m) {
        const float4 L = pts[last];             // uniform broadcast read
        float vv[8];
#pragma unroll
        for (int i = 0; i < 8; ++i) {
            float dx = __fsub_rn(rx[i], L.x);
            float dy = __fsub_rn(ry[i], L.y);
            float dz = __fsub_rn(rz[i], L.z);
            float d = sq3(dx, dy, dz);
            float v = fminf(md[i], d);
            md[i] = v;
            vv[i] = v;
        }
        // depth-3 pairwise tree; strict '>' keeps the smaller i (smaller j) on ties
        float nv[4]; int ni[4];
#pragma unroll
        for (int i = 0; i < 4; ++i) {
            bool c = vv[2 * i + 1] > vv[2 * i];
            nv[i] = c ? vv[2 * i + 1] : vv[2 * i];
            ni[i] = 2 * i + (c ? 1 : 0);
        }
        float mv[2]; int mi[2];
#pragma unroll
        for (int i = 0; i < 2; ++i) {
            bool c = nv[2 * i + 1] > nv[2 * i];
            mv[i] = c ? nv[2 * i + 1] : nv[2 * i];
            mi[i] = c ? ni[2 * i + 1] : ni[2 * i];
        }
        bool cf = mv[1] > mv[0];
        float bv = cf ? mv[1] : mv[0];
        int bi = cf ? mi[1] : mi[0];

        // DPP wave-max (pure VALU); lane 63 holds the wave max
        float wxv = bv;
        DPP_MAX(wxv, 0x111);   // row_shr:1
        DPP_MAX(wxv, 0x112);   // row_shr:2
        DPP_MAX(wxv, 0x114);   // row_shr:4
        DPP_MAX(wxv, 0x118);   // row_shr:8
        DPP_MAX(wxv, 0x142);   // row_bcast:15
        DPP_MAX(wxv, 0x143);   // row_bcast:31
        float wmax = __int_as_float(
            __builtin_amdgcn_readlane(__float_as_int(wxv), 63));

        // lowest tied lane == smallest point index (contiguous ownership)
        unsigned long long tie = __ballot(bv == wmax);
        int wl = __ffsll(tie) - 1;                                  // uniform
        int biw = __builtin_amdgcn_readlane(bi, wl);                // uniform
        unsigned jw = ((unsigned)w << 9) + ((unsigned)wl << 3) + (unsigned)biw;
        unsigned long long key =
            ((unsigned long long)__float_as_uint(wmax) << 32) |
            (unsigned long long)(0xFFFFFFFFu - jw);

        const int par = m & 1;
        if ((t & 63) == 0) red[par][w] = key;
        __syncthreads();

        unsigned long long gk = red[par][0];
#pragma unroll
        for (int ww = 1; ww < 8; ++ww) {
            unsigned long long k2 = red[par][ww];
            gk = (k2 > gk) ? k2 : gk;
        }
        last = (int)(0xFFFFFFFFu - (unsigned)(gk & 0xFFFFFFFFull));
        if (t == 0) s_idx[m] = last;
        // red ping-pongs on parity; one barrier per iteration is race-free
    }
    __syncthreads();

    for (int m = t; m < NM; m += 512) {
        int j = s_idx[m];
        size_t o = (size_t)(b * NM + m);
        float4 q = pts[j];
        pos_s[o * 3 + 0] = q.x;
        pos_s[o * 3 + 1] = q.y;
        pos_s[o * 3 + 2] = q.z;
        batch_s[o] = (float)b;
    }
}

// ---------------------------------------------------------------------------
// Kernel 2: radius ball query + exact K-nearest-within-R set per centroid.
// One wave per centroid; 4 waves per block. Selection = binary search on the
// distance-bit threshold (output order is irrelevant: result is max-pooled).
// ---------------------------------------------------------------------------
__global__ __launch_bounds__(256, 1)
void ball_kernel(const float4* __restrict__ p4,
                 const float* __restrict__ pos_s,
                 int* __restrict__ nbr,
                 int* __restrict__ cnt_out)
{
    __shared__ unsigned long long cand[4][CAND_CAP];
    const float R2 = 0.04f;  // f32(R*R)

    const int wv = threadIdx.x >> 6;
    const int lane = threadIdx.x & 63;
    const int c = blockIdx.x * 4 + wv;         // centroid id in [0, B*M)
    const int b = c >> 11;                     // / NM
    const float4* pc = p4 + b * NP;

    const float sx = pos_s[c * 3 + 0];
    const float sy = pos_s[c * 3 + 1];
    const float sz = pos_s[c * 3 + 2];
    const float ps2 = sq3(sx, sy, sz);

    int n = 0;
    for (int j0 = 0; j0 < NP; j0 += 64) {
        int j = j0 + lane;
        float4 q = pc[j];
        float dot = __fadd_rn(__fadd_rn(__fmul_rn(sx, q.x), __fmul_rn(sy, q.y)),
                              __fmul_rn(sz, q.z));
        float d2 = __fsub_rn(__fadd_rn(ps2, q.w), __fmul_rn(2.0f, dot));
        d2 = fmaxf(d2, 0.0f);
        bool in = (d2 <= R2);
        unsigned long long mask = __ballot(in);
        if (in) {
            int off = __popcll(mask & ((1ull << lane) - 1ull));
            int slot = n + off;
            if (slot < CAND_CAP)
                cand[wv][slot] =
                    ((unsigned long long)__float_as_uint(d2) << 32) |
                    (unsigned long long)(unsigned)j;
        }
        n += __popcll(mask);
    }
    if (n > CAND_CAP) n = CAND_CAP;

    int* nb = nbr + (size_t)c * NK;
    if (n <= NK) {
        for (int i = lane; i < n; i += 64)
            nb[i] = (int)(cand[wv][i] & 0xFFFFFFFFull);
        if (lane == 0) cnt_out[c] = n;
    } else if (n <= 256) {
        unsigned long long k0 = cand[wv][lane];
        unsigned long long k1 = (lane + 64  < n) ? cand[wv][lane + 64]  : ~0ull;
        unsigned long long k2 = (lane + 128 < n) ? cand[wv][lane + 128] : ~0ull;
        unsigned long long k3 = (lane + 192 < n) ? cand[wv][lane + 192] : ~0ull;
        unsigned d0 = (unsigned)(k0 >> 32), d1 = (unsigned)(k1 >> 32);
        unsigned d2b = (unsigned)(k2 >> 32), d3 = (unsigned)(k3 >> 32);

        unsigned lo = 0u, hi = __float_as_uint(R2) + 1u;
        while (hi - lo > 1u) {
            unsigned mid = (lo + hi) >> 1;
            int cc = (int)(d0 < mid) + (int)(d1 < mid) +
                     (int)(d2b < mid) + (int)(d3 < mid);
            int tot = __popcll(__ballot(cc > 0)) + __popcll(__ballot(cc > 1)) +
                      __popcll(__ballot(cc > 2)) + __popcll(__ballot(cc > 3));
            if (tot >= NK) hi = mid; else lo = mid;
        }
        const unsigned D = lo;
        bool l0 = d0 < D, l1 = d1 < D, l2 = d2b < D, l3 = d3 < D;
        bool e0 = d0 == D, e1 = d1 == D, e2 = d2b == D, e3 = d3 == D;
        int mcnt = __popcll(__ballot(l0)) + __popcll(__ballot(l1)) +
                   __popcll(__ballot(l2)) + __popcll(__ballot(l3));
        int t64 = NK - mcnt;
        unsigned long long E0 = __ballot(e0), E1 = __ballot(e1);
        unsigned long long E2 = __ballot(e2), E3 = __ballot(e3);
        unsigned long long lt = (1ull << lane) - 1ull;
        int p0 = __popcll(E0), p1 = __popcll(E1), p2 = __popcll(E2);
        bool t0 = e0 && (__popcll(E0 & lt) < t64);
        bool t1 = e1 && (p0 + __popcll(E1 & lt) < t64);
        bool t2 = e2 && (p0 + p1 + __popcll(E2 & lt) < t64);
        bool t3 = e3 && (p0 + p1 + p2 + __popcll(E3 & lt) < t64);
        bool i0 = l0 || t0, i1 = l1 || t1, i2 = l2 || t2, i3 = l3 || t3;
        unsigned long long M0 = __ballot(i0), M1 = __ballot(i1);
        unsigned long long M2 = __ballot(i2), M3 = __ballot(i3);
        int b1 = __popcll(M0), b2 = b1 + __popcll(M1), b3 = b2 + __popcll(M2);
        if (i0) nb[__popcll(M0 & lt)]      = (int)(k0 & 0xFFFFFFFFull);
        if (i1) nb[b1 + __popcll(M1 & lt)] = (int)(k1 & 0xFFFFFFFFull);
        if (i2) nb[b2 + __popcll(M2 & lt)] = (int)(k2 & 0xFFFFFFFFull);
        if (i3) nb[b3 + __popcll(M3 & lt)] = (int)(k3 & 0xFFFFFFFFull);
        if (lane == 0) cnt_out[c] = NK;
    } else {
        for (int r = 0; r < NK; ++r) {
            unsigned long long lmin = ~0ull;
            int lslot = -1;
            for (int i = lane; i < n; i += 64) {
                unsigned long long v = cand[wv][i];
                if (v < lmin) { lmin = v; lslot = i; }
            }
            unsigned long long gmin = lmin;
#pragma unroll
            for (int o = 32; o > 0; o >>= 1) {
                unsigned long long other = __shfl_xor(gmin, o, 64);
                gmin = (other < gmin) ? other : gmin;
            }
            if (lmin == gmin && lslot >= 0) {
                cand[wv][lslot] = ~0ull;
                nb[r] = (int)(gmin & 0xFFFFFFFFull);
            }
        }
        if (lane == 0) cnt_out[c] = NK;
    }
}

// ---------------------------------------------------------------------------
// Kernel 3: gather + 3-layer MLP (f32) + masked max-pool. One block per
// centroid, 2 blocks/CU. Hidden layers stored [f][n] with a row-dependent
// column-slot XOR swizzle; layer outputs written as float4 (bank-floor).
// ---------------------------------------------------------------------------
static __device__ __forceinline__ int swz(int row, int col) {
    int q = row >> 4;
    return row * MSG_LD + (col ^ ((q & 3) << 2) ^ ((q & 1) << 4));
}

__global__ __launch_bounds__(256, 2)
void mlp_kernel(const float* __restrict__ x,
                const float4* __restrict__ p4,
                const float* __restrict__ W1, const float* __restrict__ B1,
                const float* __restrict__ W2, const float* __restrict__ B2,
                const float* __restrict__ W3, const float* __restrict__ B3,
                const int* __restrict__ nbr, const int* __restrict__ cnt_arr,
                const float* __restrict__ pos_s,
                float* __restrict__ out)
{
    __shared__ __attribute__((aligned(16))) float sW1[67 * 64];
    __shared__ __attribute__((aligned(16))) float sW2[64 * 64];
    __shared__ float sB1[64], sB2[64], sB3[128];
    __shared__ __attribute__((aligned(16))) float msg[67 * MSG_LD]; // also hB
    __shared__ __attribute__((aligned(16))) float hA[64 * MSG_LD];
    __shared__ int obuf[128];
    __shared__ int s_nb[64];

    const int t = threadIdx.x;
    const int c = blockIdx.x;
    const int b = c >> 11;
    const int cnt = cnt_arr[c];
    float* hB = msg;   // msg is dead after layer 1; reuse for layer-2 output

    if (t < 128) obuf[t] = 0;
    if (t < 64) s_nb[t] = (t < cnt) ? nbr[(size_t)c * NK + t] : -1;
    {
        const float4* W1v = (const float4*)W1;
        const float4* W2v = (const float4*)W2;
        float4* s1 = (float4*)sW1;
        float4* s2 = (float4*)sW2;
        for (int i = t; i < 67 * 16; i += 256) s1[i] = W1v[i];
        for (int i = t; i < 64 * 16; i += 256) s2[i] = W2v[i];
    }
    if (t < 64) { sB1[t] = B1[t]; sB2[t] = B2[t]; }
    if (t < 128) sB3[t] = B3[t];
    const float sx = pos_s[c * 3 + 0];
    const float sy = pos_s[c * 3 + 1];
    const float sz = pos_s[c * 3 + 2];
    __syncthreads();

    // gather x_j -> msg rows 0..63 (swizzled cols), rel -> rows 64..66
    {
        int n = t >> 2, q = t & 3;
        int j = s_nb[n];
        const float4* row = (const float4*)(x + ((size_t)b * NP + (j < 0 ? 0 : j)) * NC);
#pragma unroll
        for (int s = 0; s < 4; ++s) {
            int k4 = q * 4 + s;
            float4 v = (j >= 0) ? row[k4] : make_float4(0.f, 0.f, 0.f, 0.f);
            msg[swz(k4 * 4 + 0, n)] = v.x;
            msg[swz(k4 * 4 + 1, n)] = v.y;
            msg[swz(k4 * 4 + 2, n)] = v.z;
            msg[swz(k4 * 4 + 3, n)] = v.w;
        }
        if (t < 64) {
            int jj = s_nb[t];
            float rx = 0.f, ry = 0.f, rz = 0.f;
            if (jj >= 0) {
                float4 pj = p4[b * NP + jj];
                rx = __fsub_rn(pj.x, sx);
                ry = __fsub_rn(pj.y, sy);
                rz = __fsub_rn(pj.z, sz);
            }
            msg[swz(64, t)] = rx;
            msg[swz(65, t)] = ry;
            msg[swz(66, t)] = rz;
        }
    }
    __syncthreads();

    const int tn = (t >> 4) << 2;   // n0: 4 neighbors
    const int tf = (t & 15) << 2;   // f0: 4 features

    // ---- layer 1: [64n x 67k] @ [67k x 64f] -> hA
    {
        float acc[4][4];
#pragma unroll
        for (int i = 0; i < 4; ++i)
#pragma unroll
            for (int j = 0; j < 4; ++j) acc[i][j] = 0.f;
        for (int k = 0; k < 67; ++k) {
            float4 a = *(const float4*)&msg[swz(k, tn)];
            float4 w = *(const float4*)&sW1[k * 64 + tf];
            float av[4] = {a.x, a.y, a.z, a.w};
            float wv[4] = {w.x, w.y, w.z, w.w};
#pragma unroll
            for (int i = 0; i < 4; ++i)
#pragma unroll
                for (int j = 0; j < 4; ++j)
                    acc[i][j] = fmaf(av[i], wv[j], acc[i][j]);
        }
#pragma unroll
        for (int j = 0; j < 4; ++j) {
            float bias = sB1[tf + j];
            float4 o4 = make_float4(fmaxf(acc[0][j] + bias, 0.f),
                                    fmaxf(acc[1][j] + bias, 0.f),
                                    fmaxf(acc[2][j] + bias, 0.f),
                                    fmaxf(acc[3][j] + bias, 0.f));
            *(float4*)&hA[swz(tf + j, tn)] = o4;
        }
    }
    __syncthreads();

    // ---- layer 2: [64n x 64k] @ [64k x 64f] -> hB (aliases msg)
    {
        float acc[4][4];
#pragma unroll
        for (int i = 0; i < 4; ++i)
#pragma unroll
            for (int j = 0; j < 4; ++j) acc[i][j] = 0.f;
        for (int k = 0; k < 64; ++k) {
            float4 a = *(const float4*)&hA[swz(k, tn)];
            float4 w = *(const float4*)&sW2[k * 64 + tf];
            float av[4] = {a.x, a.y, a.z, a.w};
            float wv[4] = {w.x, w.y, w.z, w.w};
#pragma unroll
            for (int i = 0; i < 4; ++i)
#pragma unroll
                for (int j = 0; j < 4; ++j)
                    acc[i][j] = fmaf(av[i], wv[j], acc[i][j]);
        }
#pragma unroll
        for (int j = 0; j < 4; ++j) {
            float bias = sB2[tf + j];
            float4 o4 = make_float4(fmaxf(acc[0][j] + bias, 0.f),
                                    fmaxf(acc[1][j] + bias, 0.f),
                                    fmaxf(acc[2][j] + bias, 0.f),
                                    fmaxf(acc[3][j] + bias, 0.f));
            *(float4*)&hB[swz(tf + j, tn)] = o4;
        }
    }
    __syncthreads();

    // ---- layer 3: [64n x 64k] @ [64k x 128f] + masked max-pool (W3 from L2)
    {
        const int tf3 = (t & 15) << 3;  // 8 features
        const float4* W3v = (const float4*)W3;
        const int wbase = (t & 15) << 1;
        float acc[4][8];
#pragma unroll
        for (int i = 0; i < 4; ++i)
#pragma unroll
            for (int j = 0; j < 8; ++j) acc[i][j] = 0.f;
#pragma unroll 4
        for (int k = 0; k < 64; ++k) {
            float4 a = *(const float4*)&hB[swz(k, tn)];
            float4 w0 = W3v[k * 32 + wbase];
            float4 w1 = W3v[k * 32 + wbase + 1];
            float av[4] = {a.x, a.y, a.z, a.w};
            float wv[8] = {w0.x, w0.y, w0.z, w0.w, w1.x, w1.y, w1.z, w1.w};
#pragma unroll
            for (int i = 0; i < 4; ++i)
#pragma unroll
                for (int j = 0; j < 8; ++j)
                    acc[i][j] = fmaf(av[i], wv[j], acc[i][j]);
        }
#pragma unroll
        for (int j = 0; j < 8; ++j) {
            float bias = sB3[tf3 + j];
            float mx = -1.f;
#pragma unroll
            for (int i = 0; i < 4; ++i) {
                if (tn + i < cnt) {
                    float v = fmaxf(acc[i][j] + bias, 0.f);
                    mx = fmaxf(mx, v);
                }
            }
            if (mx >= 0.f) atomicMax(&obuf[tf3 + j], __float_as_int(mx));
        }
    }
    __syncthreads();
    if (t < 128) out[(size_t)c * NOUT + t] = __int_as_float(obuf[t]);
}

// ---------------------------------------------------------------------------
extern "C" void kernel_launch(void* const* d_in, const int* in_sizes, int n_in,
                              void* d_out, int out_size, void* d_ws, size_t ws_size,
                              hipStream_t stream)
{
    (void)in_sizes; (void)n_in; (void)out_size; (void)ws_size;
    const float* x   = (const float*)d_in[0];
    const float* pos = (const float*)d_in[1];
    // d_in[2] = batch (unused: batch[b][n] == b)
    const float* W1 = (const float*)d_in[3];
    const float* B1 = (const float*)d_in[4];
    const float* W2 = (const float*)d_in[5];
    const float* B2 = (const float*)d_in[6];
    const float* W3 = (const float*)d_in[7];
    const float* B3 = (const float*)d_in[8];

    float* out     = (float*)d_out;                       // [B,M,128]
    float* pos_s   = out + (size_t)NB * NM * NOUT;        // [B,M,3]
    float* batch_s = pos_s + (size_t)NB * NM * 3;         // [B,M]

    // workspace: p4 table (512 KB) | nbr (4 MB) | cnt (64 KB)  ~= 4.6 MB
    float4* p4 = (float4*)d_ws;
    int* nbr = (int*)((char*)d_ws + (512 << 10));
    int* cnt = (int*)((char*)d_ws + (512 << 10) + (4 << 20));

    fps_kernel<<<NB, 512, 0, stream>>>(pos, p4, pos_s, batch_s);
    ball_kernel<<<(NB * NM) / 4, 256, 0, stream>>>(p4, pos_s, nbr, cnt);
    mlp_kernel<<<NB * NM, 256, 0, stream>>>(x, p4, W1, B1, W2, B2, W3, B3,
                                            nbr, cnt, pos_s, out);
}

// Round 7
// 1992.590 us; speedup vs baseline: 1.4882x; 1.0237x over previous
//
#include <hip/hip_runtime.h>
#include <cstdint>
#include <cstddef>

// Problem constants (match reference)
#define NB 8          // B clouds
#define NP 4096       // N points per cloud
#define NC 64         // C feature channels
#define NM 2048       // M sampled centroids
#define NK 64         // K max neighbors
#define H1 64
#define H2 64
#define NOUT 128
#define CAND_CAP 1024
#define MSG_LD 68     // padded LDS leading dim

static __device__ __forceinline__ float sq3(float x, float y, float z) {
    // ((x*x + y*y) + z*z) with no FMA contraction, matching numpy order
    return __fadd_rn(__fadd_rn(__fmul_rn(x, x), __fmul_rn(y, y)), __fmul_rn(z, z));
}

// f32 max with DPP-shifted partner; old = own value so invalid lanes are identity
#define DPP_MAX(x, ctrl)                                                       \
    do {                                                                       \
        int _yi = __builtin_amdgcn_update_dpp(__float_as_int(x),               \
                                              __float_as_int(x), (ctrl),       \
                                              0xf, 0xf, false);                \
        (x) = fmaxf((x), __int_as_float(_yi));                                 \
    } while (0)

// ---------------------------------------------------------------------------
// Kernel 1: exact FPS per cloud (8 blocks x 512 threads).
// Contiguous ownership (thread t owns j = 8t..8t+7). Per iteration:
//   - pure fmax tree + DPP wave-max (no index tracking on the hot path)
//   - tied lanes only: in-lane index via priority chain; smallest-j lane via
//     readfirstlane (lane order == j order)
//   - cross-wave reduce: single ds_max_u64 into smax[m%4]; after the barrier
//     ONE uniform LDS read yields the global argmax.
// Slot rotation: iter m atomics smax[m%4], resets smax[(m+2)%4]. Readers of
// slot (m+2)%4 were iter m-2, whose reads sit before BARRIER_{m-1}; the reset
// sits after it -> race-free. Next user is iter m+2 (after BARRIER_{m+1}).
// Key = (value_bits<<32)|(0xFFFFFFFF-j): max key == argmax with smallest-j
// tie-break == jnp.argmax semantics (non-negative floats order as uints).
// ---------------------------------------------------------------------------
__global__ __launch_bounds__(512, 1)
void fps_kernel(const float* __restrict__ pos,
                float4* __restrict__ p4,
                float* __restrict__ pos_s,
                float* __restrict__ batch_s)
{
    __shared__ float4 pts[NP];                  // 64 KB
    __shared__ int s_idx[NM];                   // 8 KB
    __shared__ unsigned long long smax[4];

    const int b = blockIdx.x;
    const int t = threadIdx.x;
    const float* p = pos + (size_t)b * NP * 3;

    for (int j = t; j < NP; j += 512) {
        float x = p[j * 3 + 0], y = p[j * 3 + 1], z = p[j * 3 + 2];
        float4 q = make_float4(x, y, z, sq3(x, y, z));
        pts[j] = q;
        p4[b * NP + j] = q;
    }
    if (t == 0) s_idx[0] = 0;
    if (t < 4) smax[t] = 0ull;
    __syncthreads();

    // thread t owns points j = 8t + i, i in 0..7 (ascending i == ascending j)
    float rx[8], ry[8], rz[8], md[8];
#pragma unroll
    for (int i = 0; i < 8; ++i) {
        float4 q = pts[(t << 3) + i];
        rx[i] = q.x; ry[i] = q.y; rz[i] = q.z;
        md[i] = __builtin_inff();
    }

    int last = 0;
    int s = 1;                                  // m % 4, starting at m = 1

    for (int m = 1; m < NM; ++m) {
        const float4 L = pts[last];             // uniform broadcast read
#pragma unroll
        for (int i = 0; i < 8; ++i) {
            float dx = __fsub_rn(rx[i], L.x);
            float dy = __fsub_rn(ry[i], L.y);
            float dz = __fsub_rn(rz[i], L.z);
            float d = sq3(dx, dy, dz);
            md[i] = fminf(md[i], d);
        }
        // pure value max tree (7 fmax, no index bookkeeping)
        float a0 = fmaxf(md[0], md[1]);
        float a1 = fmaxf(md[2], md[3]);
        float a2 = fmaxf(md[4], md[5]);
        float a3 = fmaxf(md[6], md[7]);
        float bv = fmaxf(fmaxf(a0, a1), fmaxf(a2, a3));

        // DPP wave-max (pure VALU); lane 63 holds the wave max
        float wxv = bv;
        DPP_MAX(wxv, 0x111);   // row_shr:1
        DPP_MAX(wxv, 0x112);   // row_shr:2
        DPP_MAX(wxv, 0x114);   // row_shr:4
        DPP_MAX(wxv, 0x118);   // row_shr:8
        DPP_MAX(wxv, 0x142);   // row_bcast:15
        DPP_MAX(wxv, 0x143);   // row_bcast:31
        float wmax = __int_as_float(
            __builtin_amdgcn_readlane(__float_as_int(wxv), 63));

        if (bv == wmax) {
            // in-lane smallest index achieving bv (descending scan: lowest wins)
            int bi = 7;
#pragma unroll
            for (int i = 6; i >= 0; --i) bi = (md[i] == bv) ? i : bi;
            unsigned pj = ((unsigned)t << 3) + (unsigned)bi;
            // first active lane == smallest j among tied lanes
            unsigned jw = __builtin_amdgcn_readfirstlane(pj);
            if (pj == jw) {
                unsigned long long key =
                    ((unsigned long long)__float_as_uint(wmax) << 32) |
                    (unsigned long long)(0xFFFFFFFFu - jw);
                atomicMax(&smax[s], key);
            }
        }
        int r = s + 2; if (r >= 4) r -= 4;
        if (t == 0) smax[r] = 0ull;             // reset slot for iter m+2
        __syncthreads();

        unsigned long long gk = smax[s];        // single uniform broadcast read
        last = (int)(0xFFFFFFFFu - (unsigned)(gk & 0xFFFFFFFFull));
        if (t == 0) s_idx[m] = last;
        s = s + 1; if (s == 4) s = 0;
    }
    __syncthreads();

    for (int m = t; m < NM; m += 512) {
        int j = s_idx[m];
        size_t o = (size_t)(b * NM + m);
        float4 q = pts[j];
        pos_s[o * 3 + 0] = q.x;
        pos_s[o * 3 + 1] = q.y;
        pos_s[o * 3 + 2] = q.z;
        batch_s[o] = (float)b;
    }
}

// ---------------------------------------------------------------------------
// Kernel 2: radius ball query + exact K-nearest-within-R set per centroid.
// One wave per centroid; 4 waves per block. Selection = binary search on the
// distance-bit threshold (output order is irrelevant: result is max-pooled).
// ---------------------------------------------------------------------------
__global__ __launch_bounds__(256, 1)
void ball_kernel(const float4* __restrict__ p4,
                 const float* __restrict__ pos_s,
                 int* __restrict__ nbr,
                 int* __restrict__ cnt_out)
{
    __shared__ unsigned long long cand[4][CAND_CAP];
    const float R2 = 0.04f;  // f32(R*R)

    const int wv = threadIdx.x >> 6;
    const int lane = threadIdx.x & 63;
    const int c = blockIdx.x * 4 + wv;         // centroid id in [0, B*M)
    const int b = c >> 11;                     // / NM
    const float4* pc = p4 + b * NP;

    const float sx = pos_s[c * 3 + 0];
    const float sy = pos_s[c * 3 + 1];
    const float sz = pos_s[c * 3 + 2];
    const float ps2 = sq3(sx, sy, sz);

    int n = 0;
    for (int j0 = 0; j0 < NP; j0 += 64) {
        int j = j0 + lane;
        float4 q = pc[j];
        float dot = __fadd_rn(__fadd_rn(__fmul_rn(sx, q.x), __fmul_rn(sy, q.y)),
                              __fmul_rn(sz, q.z));
        float d2 = __fsub_rn(__fadd_rn(ps2, q.w), __fmul_rn(2.0f, dot));
        d2 = fmaxf(d2, 0.0f);
        bool in = (d2 <= R2);
        unsigned long long mask = __ballot(in);
        if (in) {
            int off = __popcll(mask & ((1ull << lane) - 1ull));
            int slot = n + off;
            if (slot < CAND_CAP)
                cand[wv][slot] =
                    ((unsigned long long)__float_as_uint(d2) << 32) |
                    (unsigned long long)(unsigned)j;
        }
        n += __popcll(mask);
    }
    if (n > CAND_CAP) n = CAND_CAP;

    int* nb = nbr + (size_t)c * NK;
    if (n <= NK) {
        for (int i = lane; i < n; i += 64)
            nb[i] = (int)(cand[wv][i] & 0xFFFFFFFFull);
        if (lane == 0) cnt_out[c] = n;
    } else if (n <= 256) {
        unsigned long long k0 = cand[wv][lane];
        unsigned long long k1 = (lane + 64  < n) ? cand[wv][lane + 64]  : ~0ull;
        unsigned long long k2 = (lane + 128 < n) ? cand[wv][lane + 128] : ~0ull;
        unsigned long long k3 = (lane + 192 < n) ? cand[wv][lane + 192] : ~0ull;
        unsigned d0 = (unsigned)(k0 >> 32), d1 = (unsigned)(k1 >> 32);
        unsigned d2b = (unsigned)(k2 >> 32), d3 = (unsigned)(k3 >> 32);

        unsigned lo = 0u, hi = __float_as_uint(R2) + 1u;
        while (hi - lo > 1u) {
            unsigned mid = (lo + hi) >> 1;
            int cc = (int)(d0 < mid) + (int)(d1 < mid) +
                     (int)(d2b < mid) + (int)(d3 < mid);
            int tot = __popcll(__ballot(cc > 0)) + __popcll(__ballot(cc > 1)) +
                      __popcll(__ballot(cc > 2)) + __popcll(__ballot(cc > 3));
            if (tot >= NK) hi = mid; else lo = mid;
        }
        const unsigned D = lo;
        bool l0 = d0 < D, l1 = d1 < D, l2 = d2b < D, l3 = d3 < D;
        bool e0 = d0 == D, e1 = d1 == D, e2 = d2b == D, e3 = d3 == D;
        int mcnt = __popcll(__ballot(l0)) + __popcll(__ballot(l1)) +
                   __popcll(__ballot(l2)) + __popcll(__ballot(l3));
        int t64 = NK - mcnt;
        unsigned long long E0 = __ballot(e0), E1 = __ballot(e1);
        unsigned long long E2 = __ballot(e2), E3 = __ballot(e3);
        unsigned long long lt = (1ull << lane) - 1ull;
        int p0 = __popcll(E0), p1 = __popcll(E1), p2 = __popcll(E2);
        bool t0 = e0 && (__popcll(E0 & lt) < t64);
        bool t1 = e1 && (p0 + __popcll(E1 & lt) < t64);
        bool t2 = e2 && (p0 + p1 + __popcll(E2 & lt) < t64);
        bool t3 = e3 && (p0 + p1 + p2 + __popcll(E3 & lt) < t64);
        bool i0 = l0 || t0, i1 = l1 || t1, i2 = l2 || t2, i3 = l3 || t3;
        unsigned long long M0 = __ballot(i0), M1 = __ballot(i1);
        unsigned long long M2 = __ballot(i2), M3 = __ballot(i3);
        int b1 = __popcll(M0), b2 = b1 + __popcll(M1), b3 = b2 + __popcll(M2);
        if (i0) nb[__popcll(M0 & lt)]      = (int)(k0 & 0xFFFFFFFFull);
        if (i1) nb[b1 + __popcll(M1 & lt)] = (int)(k1 & 0xFFFFFFFFull);
        if (i2) nb[b2 + __popcll(M2 & lt)] = (int)(k2 & 0xFFFFFFFFull);
        if (i3) nb[b3 + __popcll(M3 & lt)] = (int)(k3 & 0xFFFFFFFFull);
        if (lane == 0) cnt_out[c] = NK;
    } else {
        for (int r = 0; r < NK; ++r) {
            unsigned long long lmin = ~0ull;
            int lslot = -1;
            for (int i = lane; i < n; i += 64) {
                unsigned long long v = cand[wv][i];
                if (v < lmin) { lmin = v; lslot = i; }
            }
            unsigned long long gmin = lmin;
#pragma unroll
            for (int o = 32; o > 0; o >>= 1) {
                unsigned long long other = __shfl_xor(gmin, o, 64);
                gmin = (other < gmin) ? other : gmin;
            }
            if (lmin == gmin && lslot >= 0) {
                cand[wv][lslot] = ~0ull;
                nb[r] = (int)(gmin & 0xFFFFFFFFull);
            }
        }
        if (lane == 0) cnt_out[c] = NK;
    }
}

// ---------------------------------------------------------------------------
// Kernel 3: gather + 3-layer MLP (f32) + masked max-pool. One block per
// centroid, 2 blocks/CU. Hidden layers stored [f][n] with a row-dependent
// column-slot XOR swizzle; layer outputs written as float4 (bank-floor).
// ---------------------------------------------------------------------------
static __device__ __forceinline__ int swz(int row, int col) {
    int q = row >> 4;
    return row * MSG_LD + (col ^ ((q & 3) << 2) ^ ((q & 1) << 4));
}

__global__ __launch_bounds__(256, 2)
void mlp_kernel(const float* __restrict__ x,
                const float4* __restrict__ p4,
                const float* __restrict__ W1, const float* __restrict__ B1,
                const float* __restrict__ W2, const float* __restrict__ B2,
                const float* __restrict__ W3, const float* __restrict__ B3,
                const int* __restrict__ nbr, const int* __restrict__ cnt_arr,
                const float* __restrict__ pos_s,
                float* __restrict__ out)
{
    __shared__ __attribute__((aligned(16))) float sW1[67 * 64];
    __shared__ __attribute__((aligned(16))) float sW2[64 * 64];
    __shared__ float sB1[64], sB2[64], sB3[128];
    __shared__ __attribute__((aligned(16))) float msg[67 * MSG_LD]; // also hB
    __shared__ __attribute__((aligned(16))) float hA[64 * MSG_LD];
    __shared__ int obuf[128];
    __shared__ int s_nb[64];

    const int t = threadIdx.x;
    const int c = blockIdx.x;
    const int b = c >> 11;
    const int cnt = cnt_arr[c];
    float* hB = msg;   // msg is dead after layer 1; reuse for layer-2 output

    if (t < 128) obuf[t] = 0;
    if (t < 64) s_nb[t] = (t < cnt) ? nbr[(size_t)c * NK + t] : -1;
    {
        const float4* W1v = (const float4*)W1;
        const float4* W2v = (const float4*)W2;
        float4* s1 = (float4*)sW1;
        float4* s2 = (float4*)sW2;
        for (int i = t; i < 67 * 16; i += 256) s1[i] = W1v[i];
        for (int i = t; i < 64 * 16; i += 256) s2[i] = W2v[i];
    }
    if (t < 64) { sB1[t] = B1[t]; sB2[t] = B2[t]; }
    if (t < 128) sB3[t] = B3[t];
    const float sx = pos_s[c * 3 + 0];
    const float sy = pos_s[c * 3 + 1];
    const float sz = pos_s[c * 3 + 2];
    __syncthreads();

    // gather x_j -> msg rows 0..63 (swizzled cols), rel -> rows 64..66
    {
        int n = t >> 2, q = t & 3;
        int j = s_nb[n];
        const float4* row = (const float4*)(x + ((size_t)b * NP + (j < 0 ? 0 : j)) * NC);
#pragma unroll
        for (int s = 0; s < 4; ++s) {
            int k4 = q * 4 + s;
            float4 v = (j >= 0) ? row[k4] : make_float4(0.f, 0.f, 0.f, 0.f);
            msg[swz(k4 * 4 + 0, n)] = v.x;
            msg[swz(k4 * 4 + 1, n)] = v.y;
            msg[swz(k4 * 4 + 2, n)] = v.z;
            msg[swz(k4 * 4 + 3, n)] = v.w;
        }
        if (t < 64) {
            int jj = s_nb[t];
            float rx = 0.f, ry = 0.f, rz = 0.f;
            if (jj >= 0) {
                float4 pj = p4[b * NP + jj];
                rx = __fsub_rn(pj.x, sx);
                ry = __fsub_rn(pj.y, sy);
                rz = __fsub_rn(pj.z, sz);
            }
            msg[swz(64, t)] = rx;
            msg[swz(65, t)] = ry;
            msg[swz(66, t)] = rz;
        }
    }
    __syncthreads();

    const int tn = (t >> 4) << 2;   // n0: 4 neighbors
    const int tf = (t & 15) << 2;   // f0: 4 features

    // ---- layer 1: [64n x 67k] @ [67k x 64f] -> hA
    {
        float acc[4][4];
#pragma unroll
        for (int i = 0; i < 4; ++i)
#pragma unroll
            for (int j = 0; j < 4; ++j) acc[i][j] = 0.f;
        for (int k = 0; k < 67; ++k) {
            float4 a = *(const float4*)&msg[swz(k, tn)];
            float4 w = *(const float4*)&sW1[k * 64 + tf];
            float av[4] = {a.x, a.y, a.z, a.w};
            float wv[4] = {w.x, w.y, w.z, w.w};
#pragma unroll
            for (int i = 0; i < 4; ++i)
#pragma unroll
                for (int j = 0; j < 4; ++j)
                    acc[i][j] = fmaf(av[i], wv[j], acc[i][j]);
        }
#pragma unroll
        for (int j = 0; j < 4; ++j) {
            float bias = sB1[tf + j];
            float4 o4 = make_float4(fmaxf(acc[0][j] + bias, 0.f),
                                    fmaxf(acc[1][j] + bias, 0.f),
                                    fmaxf(acc[2][j] + bias, 0.f),
                                    fmaxf(acc[3][j] + bias, 0.f));
            *(float4*)&hA[swz(tf + j, tn)] = o4;
        }
    }
    __syncthreads();

    // ---- layer 2: [64n x 64k] @ [64k x 64f] -> hB (aliases msg)
    {
        float acc[4][4];
#pragma unroll
        for (int i = 0; i < 4; ++i)
#pragma unroll
            for (int j = 0; j < 4; ++j) acc[i][j] = 0.f;
        for (int k = 0; k < 64; ++k) {
            float4 a = *(const float4*)&hA[swz(k, tn)];
            float4 w = *(const float4*)&sW2[k * 64 + tf];
            float av[4] = {a.x, a.y, a.z, a.w};
            float wv[4] = {w.x, w.y, w.z, w.w};
#pragma unroll
            for (int i = 0; i < 4; ++i)
#pragma unroll
                for (int j = 0; j < 4; ++j)
                    acc[i][j] = fmaf(av[i], wv[j], acc[i][j]);
        }
#pragma unroll
        for (int j = 0; j < 4; ++j) {
            float bias = sB2[tf + j];
            float4 o4 = make_float4(fmaxf(acc[0][j] + bias, 0.f),
                                    fmaxf(acc[1][j] + bias, 0.f),
                                    fmaxf(acc[2][j] + bias, 0.f),
                                    fmaxf(acc[3][j] + bias, 0.f));
            *(float4*)&hB[swz(tf + j, tn)] = o4;
        }
    }
    __syncthreads();

    // ---- layer 3: [64n x 64k] @ [64k x 128f] + masked max-pool (W3 from L2)
    {
        const int tf3 = (t & 15) << 3;  // 8 features
        const float4* W3v = (const float4*)W3;
        const int wbase = (t & 15) << 1;
        float acc[4][8];
#pragma unroll
        for (int i = 0; i < 4; ++i)
#pragma unroll
            for (int j = 0; j < 8; ++j) acc[i][j] = 0.f;
#pragma unroll 4
        for (int k = 0; k < 64; ++k) {
            float4 a = *(const float4*)&hB[swz(k, tn)];
            float4 w0 = W3v[k * 32 + wbase];
            float4 w1 = W3v[k * 32 + wbase + 1];
            float av[4] = {a.x, a.y, a.z, a.w};
            float wv[8] = {w0.x, w0.y, w0.z, w0.w, w1.x, w1.y, w1.z, w1.w};
#pragma unroll
            for (int i = 0; i < 4; ++i)
#pragma unroll
                for (int j = 0; j < 8; ++j)
                    acc[i][j] = fmaf(av[i], wv[j], acc[i][j]);
        }
#pragma unroll
        for (int j = 0; j < 8; ++j) {
            float bias = sB3[tf3 + j];
            float mx = -1.f;
#pragma unroll
            for (int i = 0; i < 4; ++i) {
                if (tn + i < cnt) {
                    float v = fmaxf(acc[i][j] + bias, 0.f);
                    mx = fmaxf(mx, v);
                }
            }
            if (mx >= 0.f) atomicMax(&obuf[tf3 + j], __float_as_int(mx));
        }
    }
    __syncthreads();
    if (t < 128) out[(size_t)c * NOUT + t] = __int_as_float(obuf[t]);
}

// ---------------------------------------------------------------------------
extern "C" void kernel_launch(void* const* d_in, const int* in_sizes, int n_in,
                              void* d_out, int out_size, void* d_ws, size_t ws_size,
                              hipStream_t stream)
{
    (void)in_sizes; (void)n_in; (void)out_size; (void)ws_size;
    const float* x   = (const float*)d_in[0];
    const float* pos = (const float*)d_in[1];
    // d_in[2] = batch (unused: batch[b][n] == b)
    const float* W1 = (const float*)d_in[3];
    const float* B1 = (const float*)d_in[4];
    const float* W2 = (const float*)d_in[5];
    const float* B2 = (const float*)d_in[6];
    const float* W3 = (const float*)d_in[7];
    const float* B3 = (const float*)d_in[8];

    float* out     = (float*)d_out;                       // [B,M,128]
    float* pos_s   = out + (size_t)NB * NM * NOUT;        // [B,M,3]
    float* batch_s = pos_s + (size_t)NB * NM * 3;         // [B,M]

    // workspace: p4 table (512 KB) | nbr (4 MB) | cnt (64 KB)  ~= 4.6 MB
    float4* p4 = (float4*)d_ws;
    int* nbr = (int*)((char*)d_ws + (512 << 10));
    int* cnt = (int*)((char*)d_ws + (512 << 10) + (4 << 20));

    fps_kernel<<<NB, 512, 0, stream>>>(pos, p4, pos_s, batch_s);
    ball_kernel<<<(NB * NM) / 4, 256, 0, stream>>>(p4, pos_s, nbr, cnt);
    mlp_kernel<<<NB * NM, 256, 0, stream>>>(x, p4, W1, B1, W2, B2, W3, B3,
                                            nbr, cnt, pos_s, out);
}